// Round 1
// baseline (6803.346 us; speedup 1.0000x reference)
//
#include <hip/hip_runtime.h>
#include <hip/hip_bf16.h>

#define D 128
typedef unsigned int uint;
typedef unsigned short ushort;

__device__ __forceinline__ ushort f2bf(float f) {
    uint u = __float_as_uint(f);
    uint r = (u + 0x7fffu + ((u >> 16) & 1u)) >> 16;
    return (ushort)r;
}
__device__ __forceinline__ float bf2f(uint s) {
    return __uint_as_float(s << 16);
}

// ---- degree histogram per etype ----
__global__ void hist_k(const int* __restrict__ src, const int* __restrict__ dst,
                       int* __restrict__ cs, int* __restrict__ cd, int E) {
    int i = blockIdx.x * blockDim.x + threadIdx.x;
    if (i < E) {
        atomicAdd(&cs[src[i]], 1);
        atomicAdd(&cd[dst[i]], 1);
    }
}

// ---- rs = rsqrt(max(deg,1)) for all 4 etypes at once ----
__global__ void rs_k(const int* __restrict__ cs, const int* __restrict__ cd,
                     float* __restrict__ ro, float* __restrict__ ri, int n4) {
    int i = blockIdx.x * blockDim.x + threadIdx.x;
    if (i < n4) {
        ro[i] = rsqrtf((float)max(cs[i], 1));
        ri[i] = rsqrtf((float)max(cd[i], 1));
    }
}

// ---- CSR range allocation (order-free exclusive scan via atomics) ----
__global__ void start_k(const int* __restrict__ cd, int* __restrict__ startA,
                        int* __restrict__ cursorA, int* __restrict__ totals,
                        int N, int n4) {
    int i = blockIdx.x * blockDim.x + threadIdx.x;
    if (i < n4) {
        int e = i / N;
        int c = cd[i];
        int st = atomicAdd(&totals[e], c);
        startA[i] = st;
        cursorA[i] = st;
    }
}

// ---- CSR fill ----
__global__ void fill_k(const int* __restrict__ src, const int* __restrict__ dst,
                       int* __restrict__ cursor, int* __restrict__ csr, int E) {
    int i = blockIdx.x * blockDim.x + threadIdx.x;
    if (i < E) {
        int d = dst[i];
        int slot = atomicAdd(&cursor[d], 1);
        csr[slot] = src[i];
    }
}

// ---- y = (X @ W) * rs_out[row], stored bf16. W cached in LDS. ----
// block 256 thr, 64 rows/block, thread tile 4 rows x 8 cols (cols cg*4 and cg*4+64)
__global__ __launch_bounds__(256) void gemm_rs(const float* __restrict__ X,
                                               const float* __restrict__ Wg,
                                               const float* __restrict__ rs,
                                               ushort* __restrict__ Y, int n) {
    __shared__ float Wl[D * D];
    const int tid = threadIdx.x;
    {
        const float4* ws = (const float4*)Wg;
        float4* wd = (float4*)Wl;
#pragma unroll
        for (int i = 0; i < 16; ++i) wd[tid + i * 256] = ws[tid + i * 256];
    }
    __syncthreads();
    const int rg = tid >> 4, cg = tid & 15;
    const int r0 = blockIdx.x * 64 + rg * 4;
    const int c0 = cg * 4;
    float acc[4][8];
#pragma unroll
    for (int i = 0; i < 4; ++i)
#pragma unroll
        for (int j = 0; j < 8; ++j) acc[i][j] = 0.f;
    int rr[4];
#pragma unroll
    for (int i = 0; i < 4; ++i) {
        int r = r0 + i;
        rr[i] = r < n ? r : (n - 1);
    }
    for (int k = 0; k < D; k += 4) {
        float xa[4][4];
#pragma unroll
        for (int i = 0; i < 4; ++i)
            *(float4*)xa[i] = *(const float4*)(X + (size_t)rr[i] * D + k);
#pragma unroll
        for (int kk = 0; kk < 4; ++kk) {
            float4 w0 = *(const float4*)(Wl + (k + kk) * D + c0);
            float4 w1 = *(const float4*)(Wl + (k + kk) * D + c0 + 64);
#pragma unroll
            for (int i = 0; i < 4; ++i) {
                float x = xa[i][kk];
                acc[i][0] = fmaf(x, w0.x, acc[i][0]);
                acc[i][1] = fmaf(x, w0.y, acc[i][1]);
                acc[i][2] = fmaf(x, w0.z, acc[i][2]);
                acc[i][3] = fmaf(x, w0.w, acc[i][3]);
                acc[i][4] = fmaf(x, w1.x, acc[i][4]);
                acc[i][5] = fmaf(x, w1.y, acc[i][5]);
                acc[i][6] = fmaf(x, w1.z, acc[i][6]);
                acc[i][7] = fmaf(x, w1.w, acc[i][7]);
            }
        }
    }
#pragma unroll
    for (int i = 0; i < 4; ++i) {
        int r = r0 + i;
        if (r < n) {
            float s = rs[r];
            uint2 p0, p1;
            p0.x = (uint)f2bf(acc[i][0] * s) | ((uint)f2bf(acc[i][1] * s) << 16);
            p0.y = (uint)f2bf(acc[i][2] * s) | ((uint)f2bf(acc[i][3] * s) << 16);
            p1.x = (uint)f2bf(acc[i][4] * s) | ((uint)f2bf(acc[i][5] * s) << 16);
            p1.y = (uint)f2bf(acc[i][6] * s) | ((uint)f2bf(acc[i][7] * s) << 16);
            *(uint2*)(Y + (size_t)r * D + c0) = p0;
            *(uint2*)(Y + (size_t)r * D + c0 + 64) = p1;
        }
    }
}

// ---- fused aggregation (2 relations) + bias + optional relu + LayerNorm ----
// one wave (64 lanes) per dst row, 2 cols per lane; block = 4 rows
__global__ __launch_bounds__(256) void agg_ln(
    const ushort* __restrict__ Ya, const int* __restrict__ csrA,
    const int* __restrict__ startA, const int* __restrict__ cntA,
    const float* __restrict__ rsA, const float* __restrict__ biasA,
    const ushort* __restrict__ Yb, const int* __restrict__ csrB,
    const int* __restrict__ startB, const int* __restrict__ cntB,
    const float* __restrict__ rsB, const float* __restrict__ biasB,
    const float* __restrict__ gamma, const float* __restrict__ beta,
    float* __restrict__ OUT, int n, int act) {
    const int lane = threadIdx.x & 63;
    const int row = blockIdx.x * 4 + (threadIdx.x >> 6);
    if (row >= n) return;

    float v0, v1;
    {
        const uint* Yu = (const uint*)Ya;
        float a0 = 0.f, a1 = 0.f;
        int s = startA[row], en = s + cntA[row];
        int i = s;
        for (; i + 4 <= en; i += 4) {
            int s0 = csrA[i], s1 = csrA[i + 1], s2 = csrA[i + 2], s3 = csrA[i + 3];
            uint p0 = Yu[(size_t)s0 * 64 + lane];
            uint p1 = Yu[(size_t)s1 * 64 + lane];
            uint p2 = Yu[(size_t)s2 * 64 + lane];
            uint p3 = Yu[(size_t)s3 * 64 + lane];
            a0 += bf2f(p0 & 0xffffu) + bf2f(p1 & 0xffffu) + bf2f(p2 & 0xffffu) + bf2f(p3 & 0xffffu);
            a1 += bf2f(p0 >> 16) + bf2f(p1 >> 16) + bf2f(p2 >> 16) + bf2f(p3 >> 16);
        }
        for (; i < en; ++i) {
            uint p = Yu[(size_t)csrA[i] * 64 + lane];
            a0 += bf2f(p & 0xffffu);
            a1 += bf2f(p >> 16);
        }
        float ri = rsA[row];
        float2 b = *(const float2*)(biasA + lane * 2);
        v0 = fmaf(a0, ri, b.x);
        v1 = fmaf(a1, ri, b.y);
        if (act) { v0 = fmaxf(v0, 0.f); v1 = fmaxf(v1, 0.f); }
    }
    {
        const uint* Yu = (const uint*)Yb;
        float a0 = 0.f, a1 = 0.f;
        int s = startB[row], en = s + cntB[row];
        int i = s;
        for (; i + 4 <= en; i += 4) {
            int s0 = csrB[i], s1 = csrB[i + 1], s2 = csrB[i + 2], s3 = csrB[i + 3];
            uint p0 = Yu[(size_t)s0 * 64 + lane];
            uint p1 = Yu[(size_t)s1 * 64 + lane];
            uint p2 = Yu[(size_t)s2 * 64 + lane];
            uint p3 = Yu[(size_t)s3 * 64 + lane];
            a0 += bf2f(p0 & 0xffffu) + bf2f(p1 & 0xffffu) + bf2f(p2 & 0xffffu) + bf2f(p3 & 0xffffu);
            a1 += bf2f(p0 >> 16) + bf2f(p1 >> 16) + bf2f(p2 >> 16) + bf2f(p3 >> 16);
        }
        for (; i < en; ++i) {
            uint p = Yu[(size_t)csrB[i] * 64 + lane];
            a0 += bf2f(p & 0xffffu);
            a1 += bf2f(p >> 16);
        }
        float ri = rsB[row];
        float2 b = *(const float2*)(biasB + lane * 2);
        float t0 = fmaf(a0, ri, b.x);
        float t1 = fmaf(a1, ri, b.y);
        if (act) { t0 = fmaxf(t0, 0.f); t1 = fmaxf(t1, 0.f); }
        v0 += t0;
        v1 += t1;
    }
    // LayerNorm over 128 cols, wave-wide butterfly reduction
    float s = v0 + v1, q = v0 * v0 + v1 * v1;
#pragma unroll
    for (int off = 1; off < 64; off <<= 1) {
        s += __shfl_xor(s, off);
        q += __shfl_xor(q, off);
    }
    float m = s * (1.f / 128.f);
    float var = q * (1.f / 128.f) - m * m;
    float inv = rsqrtf(var + 1e-5f);
    float2 g = *(const float2*)(gamma + lane * 2);
    float2 be = *(const float2*)(beta + lane * 2);
    float2 o;
    o.x = fmaf((v0 - m) * inv, g.x, be.x);
    o.y = fmaf((v1 - m) * inv, g.y, be.y);
    *(float2*)(OUT + (size_t)row * D + lane * 2) = o;
}

extern "C" void kernel_launch(void* const* d_in, const int* in_sizes, int n_in,
                              void* d_out, int out_size, void* d_ws, size_t ws_size,
                              hipStream_t stream) {
    const int N = in_sizes[0] / D;
    const int E = in_sizes[8];
    const float* xA = (const float*)d_in[0];
    const float* xB = (const float*)d_in[1];
    const float* W0 = (const float*)d_in[2];
    const float* b0 = (const float*)d_in[3];
    const float* W1 = (const float*)d_in[4];
    const float* b1 = (const float*)d_in[5];
    const float* lng = (const float*)d_in[6];
    const float* lnb = (const float*)d_in[7];
    const int* srcs[4] = {(const int*)d_in[8], (const int*)d_in[10],
                          (const int*)d_in[12], (const int*)d_in[14]};
    const int* dsts[4] = {(const int*)d_in[9], (const int*)d_in[11],
                          (const int*)d_in[13], (const int*)d_in[15]};

    const size_t nd = (size_t)N * D;
    char* p = (char*)d_ws;
    ushort* y[4];
    for (int e = 0; e < 4; ++e) y[e] = (ushort*)p + e * nd;
    p += 4 * nd * sizeof(ushort);
    // cnt_src(4N) | cnt_dst(4N) | totals(16) | start(4N) | cursor(4N)  -- one memset zone for first 8N+16
    int* cnt_src = (int*)p;
    int* cnt_dst = cnt_src + 4 * (size_t)N;
    int* totals = cnt_dst + 4 * (size_t)N;
    int* startA = totals + 16;
    int* cursorA = startA + 4 * (size_t)N;
    p = (char*)(cursorA + 4 * (size_t)N);
    float* rs_out = (float*)p;
    float* rs_in = rs_out + 4 * (size_t)N;
    p = (char*)(rs_in + 4 * (size_t)N);
    int* csr = (int*)p;  // 4 * E ints

    // hA/hB live in d_out between layers (layer-1 agg only reads y, so no hazard)
    float* hA = (float*)d_out;
    float* hB = hA + nd;

    hipMemsetAsync(cnt_src, 0, (8 * (size_t)N + 16) * sizeof(int), stream);

    const int TB = 256;
    const int egrid = (E + TB - 1) / TB;
    for (int e = 0; e < 4; ++e)
        hist_k<<<egrid, TB, 0, stream>>>(srcs[e], dsts[e], cnt_src + e * (size_t)N,
                                         cnt_dst + e * (size_t)N, E);
    const int n4 = 4 * N;
    rs_k<<<(n4 + TB - 1) / TB, TB, 0, stream>>>(cnt_src, cnt_dst, rs_out, rs_in, n4);
    start_k<<<(n4 + TB - 1) / TB, TB, 0, stream>>>(cnt_dst, startA, cursorA, totals, N, n4);
    for (int e = 0; e < 4; ++e)
        fill_k<<<egrid, TB, 0, stream>>>(srcs[e], dsts[e], cursorA + e * (size_t)N,
                                         csr + (size_t)e * E, E);

    const int ggrid = (N + 63) / 64;
    const int agrid = (N + 3) / 4;

    // ---- layer 0 (act=1) ----
    gemm_rs<<<ggrid, TB, 0, stream>>>(xA, W0 + 0 * D * D, rs_out + 0 * (size_t)N, y[0], N);
    gemm_rs<<<ggrid, TB, 0, stream>>>(xA, W0 + 1 * D * D, rs_out + 1 * (size_t)N, y[1], N);
    gemm_rs<<<ggrid, TB, 0, stream>>>(xB, W0 + 2 * D * D, rs_out + 2 * (size_t)N, y[2], N);
    gemm_rs<<<ggrid, TB, 0, stream>>>(xB, W0 + 3 * D * D, rs_out + 3 * (size_t)N, y[3], N);
    // dst A: relations aa(e0), ba(e2)
    agg_ln<<<agrid, TB, 0, stream>>>(
        y[0], csr + (size_t)0 * E, startA + 0 * (size_t)N, cnt_dst + 0 * (size_t)N,
        rs_in + 0 * (size_t)N, b0 + 0 * D,
        y[2], csr + (size_t)2 * E, startA + 2 * (size_t)N, cnt_dst + 2 * (size_t)N,
        rs_in + 2 * (size_t)N, b0 + 2 * D,
        lng + 0 * D, lnb + 0 * D, hA, N, 1);
    // dst B: relations ab(e1), bb(e3)
    agg_ln<<<agrid, TB, 0, stream>>>(
        y[1], csr + (size_t)1 * E, startA + 1 * (size_t)N, cnt_dst + 1 * (size_t)N,
        rs_in + 1 * (size_t)N, b0 + 1 * D,
        y[3], csr + (size_t)3 * E, startA + 3 * (size_t)N, cnt_dst + 3 * (size_t)N,
        rs_in + 3 * (size_t)N, b0 + 3 * D,
        lng + 1 * D, lnb + 1 * D, hB, N, 1);

    // ---- layer 1 (act=0), output straight into d_out ----
    gemm_rs<<<ggrid, TB, 0, stream>>>(hA, W1 + 0 * D * D, rs_out + 0 * (size_t)N, y[0], N);
    gemm_rs<<<ggrid, TB, 0, stream>>>(hA, W1 + 1 * D * D, rs_out + 1 * (size_t)N, y[1], N);
    gemm_rs<<<ggrid, TB, 0, stream>>>(hB, W1 + 2 * D * D, rs_out + 2 * (size_t)N, y[2], N);
    gemm_rs<<<ggrid, TB, 0, stream>>>(hB, W1 + 3 * D * D, rs_out + 3 * (size_t)N, y[3], N);
    agg_ln<<<agrid, TB, 0, stream>>>(
        y[0], csr + (size_t)0 * E, startA + 0 * (size_t)N, cnt_dst + 0 * (size_t)N,
        rs_in + 0 * (size_t)N, b1 + 0 * D,
        y[2], csr + (size_t)2 * E, startA + 2 * (size_t)N, cnt_dst + 2 * (size_t)N,
        rs_in + 2 * (size_t)N, b1 + 2 * D,
        lng + 2 * D, lnb + 2 * D, hA, N, 0);
    agg_ln<<<agrid, TB, 0, stream>>>(
        y[1], csr + (size_t)1 * E, startA + 1 * (size_t)N, cnt_dst + 1 * (size_t)N,
        rs_in + 1 * (size_t)N, b1 + 1 * D,
        y[3], csr + (size_t)3 * E, startA + 3 * (size_t)N, cnt_dst + 3 * (size_t)N,
        rs_in + 3 * (size_t)N, b1 + 3 * D,
        lng + 3 * D, lnb + 3 * D, hB, N, 0);
}

// Round 2
// 2264.887 us; speedup vs baseline: 3.0038x; 3.0038x over previous
//
#include <hip/hip_runtime.h>
#include <hip/hip_bf16.h>

#define D 128
typedef unsigned int uint;
typedef unsigned short ushort;

__device__ __forceinline__ ushort f2bf(float f) {
    uint u = __float_as_uint(f);
    uint r = (u + 0x7fffu + ((u >> 16) & 1u)) >> 16;
    return (ushort)r;
}
__device__ __forceinline__ float bf2f(uint s) {
    return __uint_as_float(s << 16);
}

// ---- degree histogram per etype ----
__global__ void hist_k(const int* __restrict__ src, const int* __restrict__ dst,
                       int* __restrict__ cs, int* __restrict__ cd, int E) {
    int i = blockIdx.x * blockDim.x + threadIdx.x;
    if (i < E) {
        atomicAdd(&cs[src[i]], 1);
        atomicAdd(&cd[dst[i]], 1);
    }
}

// ---- rs = rsqrt(max(deg,1)) for all 4 etypes at once ----
__global__ void rs_k(const int* __restrict__ cs, const int* __restrict__ cd,
                     float* __restrict__ ro, float* __restrict__ ri, int n4) {
    int i = blockIdx.x * blockDim.x + threadIdx.x;
    if (i < n4) {
        ro[i] = rsqrtf((float)max(cs[i], 1));
        ri[i] = rsqrtf((float)max(cd[i], 1));
    }
}

// ---- CSR range allocation: hierarchical scan, ONE atomic per block ----
// (order across blocks irrelevant: any partition of the CSR space works)
__global__ __launch_bounds__(256) void start_e_k(const int* __restrict__ cd,
                                                 int* __restrict__ start,
                                                 int* __restrict__ cursor,
                                                 int* __restrict__ total, int N) {
    __shared__ int wsum[4];
    const int i = blockIdx.x * 256 + threadIdx.x;
    const int lane = threadIdx.x & 63;
    const int wid = threadIdx.x >> 6;
    int c = (i < N) ? cd[i] : 0;
    int inc = c;
#pragma unroll
    for (int off = 1; off < 64; off <<= 1) {
        int t = __shfl_up(inc, off);
        if (lane >= off) inc += t;
    }
    if (lane == 63) wsum[wid] = inc;
    __syncthreads();
    if (threadIdx.x == 0) {
        int s0 = wsum[0], s1 = wsum[1], s2 = wsum[2], s3 = wsum[3];
        int base = atomicAdd(total, s0 + s1 + s2 + s3);
        wsum[0] = base;
        wsum[1] = base + s0;
        wsum[2] = base + s0 + s1;
        wsum[3] = base + s0 + s1 + s2;
    }
    __syncthreads();
    int st = wsum[wid] + inc - c;
    if (i < N) {
        start[i] = st;
        cursor[i] = st;
    }
}

// ---- CSR fill ----
__global__ void fill_k(const int* __restrict__ src, const int* __restrict__ dst,
                       int* __restrict__ cursor, int* __restrict__ csr, int E) {
    int i = blockIdx.x * blockDim.x + threadIdx.x;
    if (i < E) {
        int d = dst[i];
        int slot = atomicAdd(&cursor[d], 1);
        csr[slot] = src[i];
    }
}

// ---- y = (X @ W) * rs_out[row], stored bf16. W cached in LDS. ----
__global__ __launch_bounds__(256) void gemm_rs(const float* __restrict__ X,
                                               const float* __restrict__ Wg,
                                               const float* __restrict__ rs,
                                               ushort* __restrict__ Y, int n) {
    __shared__ float Wl[D * D];
    const int tid = threadIdx.x;
    {
        const float4* ws = (const float4*)Wg;
        float4* wd = (float4*)Wl;
#pragma unroll
        for (int i = 0; i < 16; ++i) wd[tid + i * 256] = ws[tid + i * 256];
    }
    __syncthreads();
    const int rg = tid >> 4, cg = tid & 15;
    const int r0 = blockIdx.x * 64 + rg * 4;
    const int c0 = cg * 4;
    float acc[4][8];
#pragma unroll
    for (int i = 0; i < 4; ++i)
#pragma unroll
        for (int j = 0; j < 8; ++j) acc[i][j] = 0.f;
    int rr[4];
#pragma unroll
    for (int i = 0; i < 4; ++i) {
        int r = r0 + i;
        rr[i] = r < n ? r : (n - 1);
    }
    for (int k = 0; k < D; k += 4) {
        float xa[4][4];
#pragma unroll
        for (int i = 0; i < 4; ++i)
            *(float4*)xa[i] = *(const float4*)(X + (size_t)rr[i] * D + k);
#pragma unroll
        for (int kk = 0; kk < 4; ++kk) {
            float4 w0 = *(const float4*)(Wl + (k + kk) * D + c0);
            float4 w1 = *(const float4*)(Wl + (k + kk) * D + c0 + 64);
#pragma unroll
            for (int i = 0; i < 4; ++i) {
                float x = xa[i][kk];
                acc[i][0] = fmaf(x, w0.x, acc[i][0]);
                acc[i][1] = fmaf(x, w0.y, acc[i][1]);
                acc[i][2] = fmaf(x, w0.z, acc[i][2]);
                acc[i][3] = fmaf(x, w0.w, acc[i][3]);
                acc[i][4] = fmaf(x, w1.x, acc[i][4]);
                acc[i][5] = fmaf(x, w1.y, acc[i][5]);
                acc[i][6] = fmaf(x, w1.z, acc[i][6]);
                acc[i][7] = fmaf(x, w1.w, acc[i][7]);
            }
        }
    }
#pragma unroll
    for (int i = 0; i < 4; ++i) {
        int r = r0 + i;
        if (r < n) {
            float s = rs[r];
            uint2 p0, p1;
            p0.x = (uint)f2bf(acc[i][0] * s) | ((uint)f2bf(acc[i][1] * s) << 16);
            p0.y = (uint)f2bf(acc[i][2] * s) | ((uint)f2bf(acc[i][3] * s) << 16);
            p1.x = (uint)f2bf(acc[i][4] * s) | ((uint)f2bf(acc[i][5] * s) << 16);
            p1.y = (uint)f2bf(acc[i][6] * s) | ((uint)f2bf(acc[i][7] * s) << 16);
            *(uint2*)(Y + (size_t)r * D + c0) = p0;
            *(uint2*)(Y + (size_t)r * D + c0 + 64) = p1;
        }
    }
}

// ---- fused aggregation (2 relations) + bias + optional relu + LayerNorm ----
__global__ __launch_bounds__(256) void agg_ln(
    const ushort* __restrict__ Ya, const int* __restrict__ csrA,
    const int* __restrict__ startA, const int* __restrict__ cntA,
    const float* __restrict__ rsA, const float* __restrict__ biasA,
    const ushort* __restrict__ Yb, const int* __restrict__ csrB,
    const int* __restrict__ startB, const int* __restrict__ cntB,
    const float* __restrict__ rsB, const float* __restrict__ biasB,
    const float* __restrict__ gamma, const float* __restrict__ beta,
    float* __restrict__ OUT, int n, int act) {
    const int lane = threadIdx.x & 63;
    const int row = blockIdx.x * 4 + (threadIdx.x >> 6);
    if (row >= n) return;

    float v0, v1;
    {
        const uint* Yu = (const uint*)Ya;
        float a0 = 0.f, a1 = 0.f;
        int s = startA[row], en = s + cntA[row];
        int i = s;
        for (; i + 4 <= en; i += 4) {
            int s0 = csrA[i], s1 = csrA[i + 1], s2 = csrA[i + 2], s3 = csrA[i + 3];
            uint p0 = Yu[(size_t)s0 * 64 + lane];
            uint p1 = Yu[(size_t)s1 * 64 + lane];
            uint p2 = Yu[(size_t)s2 * 64 + lane];
            uint p3 = Yu[(size_t)s3 * 64 + lane];
            a0 += bf2f(p0 & 0xffffu) + bf2f(p1 & 0xffffu) + bf2f(p2 & 0xffffu) + bf2f(p3 & 0xffffu);
            a1 += bf2f(p0 >> 16) + bf2f(p1 >> 16) + bf2f(p2 >> 16) + bf2f(p3 >> 16);
        }
        for (; i < en; ++i) {
            uint p = Yu[(size_t)csrA[i] * 64 + lane];
            a0 += bf2f(p & 0xffffu);
            a1 += bf2f(p >> 16);
        }
        float ri = rsA[row];
        float2 b = *(const float2*)(biasA + lane * 2);
        v0 = fmaf(a0, ri, b.x);
        v1 = fmaf(a1, ri, b.y);
        if (act) { v0 = fmaxf(v0, 0.f); v1 = fmaxf(v1, 0.f); }
    }
    {
        const uint* Yu = (const uint*)Yb;
        float a0 = 0.f, a1 = 0.f;
        int s = startB[row], en = s + cntB[row];
        int i = s;
        for (; i + 4 <= en; i += 4) {
            int s0 = csrB[i], s1 = csrB[i + 1], s2 = csrB[i + 2], s3 = csrB[i + 3];
            uint p0 = Yu[(size_t)s0 * 64 + lane];
            uint p1 = Yu[(size_t)s1 * 64 + lane];
            uint p2 = Yu[(size_t)s2 * 64 + lane];
            uint p3 = Yu[(size_t)s3 * 64 + lane];
            a0 += bf2f(p0 & 0xffffu) + bf2f(p1 & 0xffffu) + bf2f(p2 & 0xffffu) + bf2f(p3 & 0xffffu);
            a1 += bf2f(p0 >> 16) + bf2f(p1 >> 16) + bf2f(p2 >> 16) + bf2f(p3 >> 16);
        }
        for (; i < en; ++i) {
            uint p = Yu[(size_t)csrB[i] * 64 + lane];
            a0 += bf2f(p & 0xffffu);
            a1 += bf2f(p >> 16);
        }
        float ri = rsB[row];
        float2 b = *(const float2*)(biasB + lane * 2);
        float t0 = fmaf(a0, ri, b.x);
        float t1 = fmaf(a1, ri, b.y);
        if (act) { t0 = fmaxf(t0, 0.f); t1 = fmaxf(t1, 0.f); }
        v0 += t0;
        v1 += t1;
    }
    float s = v0 + v1, q = v0 * v0 + v1 * v1;
#pragma unroll
    for (int off = 1; off < 64; off <<= 1) {
        s += __shfl_xor(s, off);
        q += __shfl_xor(q, off);
    }
    float m = s * (1.f / 128.f);
    float var = q * (1.f / 128.f) - m * m;
    float inv = rsqrtf(var + 1e-5f);
    float2 g = *(const float2*)(gamma + lane * 2);
    float2 be = *(const float2*)(beta + lane * 2);
    float2 o;
    o.x = fmaf((v0 - m) * inv, g.x, be.x);
    o.y = fmaf((v1 - m) * inv, g.y, be.y);
    *(float2*)(OUT + (size_t)row * D + lane * 2) = o;
}

extern "C" void kernel_launch(void* const* d_in, const int* in_sizes, int n_in,
                              void* d_out, int out_size, void* d_ws, size_t ws_size,
                              hipStream_t stream) {
    const int N = in_sizes[0] / D;
    const int E = in_sizes[8];
    const float* xA = (const float*)d_in[0];
    const float* xB = (const float*)d_in[1];
    const float* W0 = (const float*)d_in[2];
    const float* b0 = (const float*)d_in[3];
    const float* W1 = (const float*)d_in[4];
    const float* b1 = (const float*)d_in[5];
    const float* lng = (const float*)d_in[6];
    const float* lnb = (const float*)d_in[7];
    const int* srcs[4] = {(const int*)d_in[8], (const int*)d_in[10],
                          (const int*)d_in[12], (const int*)d_in[14]};
    const int* dsts[4] = {(const int*)d_in[9], (const int*)d_in[11],
                          (const int*)d_in[13], (const int*)d_in[15]};

    const size_t nd = (size_t)N * D;
    char* p = (char*)d_ws;
    ushort* y[4];
    for (int e = 0; e < 4; ++e) y[e] = (ushort*)p + e * nd;
    p += 4 * nd * sizeof(ushort);
    int* cnt_src = (int*)p;
    int* cnt_dst = cnt_src + 4 * (size_t)N;
    int* totals = cnt_dst + 4 * (size_t)N;
    int* startA = totals + 16;
    int* cursorA = startA + 4 * (size_t)N;
    p = (char*)(cursorA + 4 * (size_t)N);
    float* rs_out = (float*)p;
    float* rs_in = rs_out + 4 * (size_t)N;
    p = (char*)(rs_in + 4 * (size_t)N);
    int* csr = (int*)p;  // 4 * E ints

    float* hA = (float*)d_out;
    float* hB = hA + nd;

    hipMemsetAsync(cnt_src, 0, (8 * (size_t)N + 16) * sizeof(int), stream);

    const int TB = 256;
    const int egrid = (E + TB - 1) / TB;
    for (int e = 0; e < 4; ++e)
        hist_k<<<egrid, TB, 0, stream>>>(srcs[e], dsts[e], cnt_src + e * (size_t)N,
                                         cnt_dst + e * (size_t)N, E);
    const int n4 = 4 * N;
    rs_k<<<(n4 + TB - 1) / TB, TB, 0, stream>>>(cnt_src, cnt_dst, rs_out, rs_in, n4);
    const int sgrid = (N + TB - 1) / TB;
    for (int e = 0; e < 4; ++e)
        start_e_k<<<sgrid, TB, 0, stream>>>(cnt_dst + e * (size_t)N,
                                            startA + e * (size_t)N,
                                            cursorA + e * (size_t)N, &totals[e], N);
    for (int e = 0; e < 4; ++e)
        fill_k<<<egrid, TB, 0, stream>>>(srcs[e], dsts[e], cursorA + e * (size_t)N,
                                         csr + (size_t)e * E, E);

    const int ggrid = (N + 63) / 64;
    const int agrid = (N + 3) / 4;

    // ---- layer 0 (act=1) ----
    gemm_rs<<<ggrid, TB, 0, stream>>>(xA, W0 + 0 * D * D, rs_out + 0 * (size_t)N, y[0], N);
    gemm_rs<<<ggrid, TB, 0, stream>>>(xA, W0 + 1 * D * D, rs_out + 1 * (size_t)N, y[1], N);
    gemm_rs<<<ggrid, TB, 0, stream>>>(xB, W0 + 2 * D * D, rs_out + 2 * (size_t)N, y[2], N);
    gemm_rs<<<ggrid, TB, 0, stream>>>(xB, W0 + 3 * D * D, rs_out + 3 * (size_t)N, y[3], N);
    agg_ln<<<agrid, TB, 0, stream>>>(
        y[0], csr + (size_t)0 * E, startA + 0 * (size_t)N, cnt_dst + 0 * (size_t)N,
        rs_in + 0 * (size_t)N, b0 + 0 * D,
        y[2], csr + (size_t)2 * E, startA + 2 * (size_t)N, cnt_dst + 2 * (size_t)N,
        rs_in + 2 * (size_t)N, b0 + 2 * D,
        lng + 0 * D, lnb + 0 * D, hA, N, 1);
    agg_ln<<<agrid, TB, 0, stream>>>(
        y[1], csr + (size_t)1 * E, startA + 1 * (size_t)N, cnt_dst + 1 * (size_t)N,
        rs_in + 1 * (size_t)N, b0 + 1 * D,
        y[3], csr + (size_t)3 * E, startA + 3 * (size_t)N, cnt_dst + 3 * (size_t)N,
        rs_in + 3 * (size_t)N, b0 + 3 * D,
        lng + 1 * D, lnb + 1 * D, hB, N, 1);

    // ---- layer 1 (act=0) ----
    gemm_rs<<<ggrid, TB, 0, stream>>>(hA, W1 + 0 * D * D, rs_out + 0 * (size_t)N, y[0], N);
    gemm_rs<<<ggrid, TB, 0, stream>>>(hA, W1 + 1 * D * D, rs_out + 1 * (size_t)N, y[1], N);
    gemm_rs<<<ggrid, TB, 0, stream>>>(hB, W1 + 2 * D * D, rs_out + 2 * (size_t)N, y[2], N);
    gemm_rs<<<ggrid, TB, 0, stream>>>(hB, W1 + 3 * D * D, rs_out + 3 * (size_t)N, y[3], N);
    agg_ln<<<agrid, TB, 0, stream>>>(
        y[0], csr + (size_t)0 * E, startA + 0 * (size_t)N, cnt_dst + 0 * (size_t)N,
        rs_in + 0 * (size_t)N, b1 + 0 * D,
        y[2], csr + (size_t)2 * E, startA + 2 * (size_t)N, cnt_dst + 2 * (size_t)N,
        rs_in + 2 * (size_t)N, b1 + 2 * D,
        lng + 2 * D, lnb + 2 * D, hA, N, 0);
    agg_ln<<<agrid, TB, 0, stream>>>(
        y[1], csr + (size_t)1 * E, startA + 1 * (size_t)N, cnt_dst + 1 * (size_t)N,
        rs_in + 1 * (size_t)N, b1 + 1 * D,
        y[3], csr + (size_t)3 * E, startA + 3 * (size_t)N, cnt_dst + 3 * (size_t)N,
        rs_in + 3 * (size_t)N, b1 + 3 * D,
        lng + 3 * D, lnb + 3 * D, hB, N, 0);
}

// Round 3
// 1851.617 us; speedup vs baseline: 3.6743x; 1.2232x over previous
//
#include <hip/hip_runtime.h>
#include <hip/hip_bf16.h>

#define D 128
typedef unsigned int uint;
typedef unsigned short ushort;
typedef short short8 __attribute__((ext_vector_type(8)));
typedef float f32x4 __attribute__((ext_vector_type(4)));

__device__ __forceinline__ ushort f2bf(float f) {
    uint u = __float_as_uint(f);
    return (ushort)((u + 0x7fffu + ((u >> 16) & 1u)) >> 16);
}
__device__ __forceinline__ float bf2f(uint s) { return __uint_as_float(s << 16); }

// ---------------- histogram: 4 etypes, 4 edges/thread ----------------
__global__ __launch_bounds__(256) void hist4_k(
    const int* __restrict__ s0, const int* __restrict__ d0,
    const int* __restrict__ s1, const int* __restrict__ d1,
    const int* __restrict__ s2, const int* __restrict__ d2,
    const int* __restrict__ s3, const int* __restrict__ d3,
    int* __restrict__ cs, int* __restrict__ cd, int N, int E) {
    const int e = blockIdx.y;
    const int* sp = e == 0 ? s0 : e == 1 ? s1 : e == 2 ? s2 : s3;
    const int* dp = e == 0 ? d0 : e == 1 ? d1 : e == 2 ? d2 : d3;
    int* cse = cs + (size_t)e * N;
    int* cde = cd + (size_t)e * N;
    int i = (blockIdx.x * 256 + threadIdx.x) * 4;
    if (i + 4 <= E) {
        int4 s = *(const int4*)(sp + i);
        int4 d = *(const int4*)(dp + i);
        atomicAdd(&cse[s.x], 1); atomicAdd(&cse[s.y], 1);
        atomicAdd(&cse[s.z], 1); atomicAdd(&cse[s.w], 1);
        atomicAdd(&cde[d.x], 1); atomicAdd(&cde[d.y], 1);
        atomicAdd(&cde[d.z], 1); atomicAdd(&cde[d.w], 1);
    } else {
        for (; i < E; ++i) { atomicAdd(&cse[sp[i]], 1); atomicAdd(&cde[dp[i]], 1); }
    }
}

// ---------------- rs = rsqrt(max(deg,1)) ----------------
__global__ void rs_k(const int* __restrict__ cs, const int* __restrict__ cd,
                     float* __restrict__ ro, float* __restrict__ ri, int n4) {
    int i = blockIdx.x * blockDim.x + threadIdx.x;
    if (i < n4) {
        ro[i] = rsqrtf((float)max(cs[i], 1));
        ri[i] = rsqrtf((float)max(cd[i], 1));
    }
}

// ---------------- CSR start offsets: hierarchical scan, 1 atomic/block ----------------
__global__ __launch_bounds__(256) void start4_k(const int* __restrict__ cd,
                                                int* __restrict__ start,
                                                int* __restrict__ cursor,
                                                int* __restrict__ totals, int N) {
    const int e = blockIdx.y;
    const int* cde = cd + (size_t)e * N;
    int* st = start + (size_t)e * N;
    int* cu = cursor + (size_t)e * N;
    __shared__ int wsum[4];
    const int i = blockIdx.x * 256 + threadIdx.x;
    const int lane = threadIdx.x & 63;
    const int wid = threadIdx.x >> 6;
    int c = (i < N) ? cde[i] : 0;
    int inc = c;
#pragma unroll
    for (int off = 1; off < 64; off <<= 1) {
        int t = __shfl_up(inc, off);
        if (lane >= off) inc += t;
    }
    if (lane == 63) wsum[wid] = inc;
    __syncthreads();
    if (threadIdx.x == 0) {
        int v0 = wsum[0], v1 = wsum[1], v2 = wsum[2], v3 = wsum[3];
        int base = atomicAdd(&totals[e], v0 + v1 + v2 + v3);
        wsum[0] = base;
        wsum[1] = base + v0;
        wsum[2] = base + v0 + v1;
        wsum[3] = base + v0 + v1 + v2;
    }
    __syncthreads();
    int s = wsum[wid] + inc - c;
    if (i < N) { st[i] = s; cu[i] = s; }
}

// ---------------- CSR fill: 4 etypes, 4 edges/thread ----------------
__global__ __launch_bounds__(256) void fill4_k(
    const int* __restrict__ s0, const int* __restrict__ d0,
    const int* __restrict__ s1, const int* __restrict__ d1,
    const int* __restrict__ s2, const int* __restrict__ d2,
    const int* __restrict__ s3, const int* __restrict__ d3,
    int* __restrict__ cursor, int* __restrict__ csr, int N, int E) {
    const int e = blockIdx.y;
    const int* sp = e == 0 ? s0 : e == 1 ? s1 : e == 2 ? s2 : s3;
    const int* dp = e == 0 ? d0 : e == 1 ? d1 : e == 2 ? d2 : d3;
    int* cur = cursor + (size_t)e * N;
    int* out = csr + (size_t)e * E;
    int i = (blockIdx.x * 256 + threadIdx.x) * 4;
    if (i + 4 <= E) {
        int4 s = *(const int4*)(sp + i);
        int4 d = *(const int4*)(dp + i);
        out[atomicAdd(&cur[d.x], 1)] = s.x;
        out[atomicAdd(&cur[d.y], 1)] = s.y;
        out[atomicAdd(&cur[d.z], 1)] = s.z;
        out[atomicAdd(&cur[d.w], 1)] = s.w;
    } else {
        for (; i < E; ++i) out[atomicAdd(&cur[dp[i]], 1)] = sp[i];
    }
}

// ---------------- W pre-swizzle into MFMA A-operand (W^T) frag order ----------------
// WF[l*4+e][(ct*4+kf)*64+lane][j] = bf16( W[l][e][kf*32+(lane>>4)*8+j][ct*16+(lane&15)] )
__global__ __launch_bounds__(256) void wswz_k(const float* __restrict__ W0,
                                              const float* __restrict__ W1,
                                              ushort* __restrict__ WF) {
    int t = blockIdx.x * 256 + threadIdx.x;  // 16384 threads total
    int lane = t & 63, kf = (t >> 6) & 3, ct = (t >> 8) & 7, e = (t >> 11) & 3, l = (t >> 13) & 1;
    const float* Ws = (l ? W1 : W0) + (size_t)e * D * D;
    int m = lane & 15, q = lane >> 4;
    const float* src = Ws + (size_t)(kf * 32 + q * 8) * D + ct * 16 + m;
    ushort v[8];
#pragma unroll
    for (int j = 0; j < 8; ++j) v[j] = f2bf(src[(size_t)j * D]);
    uint4 pk;
    pk.x = (uint)v[0] | ((uint)v[1] << 16);
    pk.y = (uint)v[2] | ((uint)v[3] << 16);
    pk.z = (uint)v[4] | ((uint)v[5] << 16);
    pk.w = (uint)v[6] | ((uint)v[7] << 16);
    *(uint4*)(WF + ((size_t)(l * 4 + e) * 2048 + (ct * 4 + kf) * 64 + lane) * 8) = pk;
}

// ---------------- pair-fused MFMA GEMM: y[e] = bf16((X@W_e)*rs_e) for e=2p,2p+1 ----------------
__global__ __launch_bounds__(256) void gemm_pair_k(
    const float* __restrict__ XA, const float* __restrict__ XB,
    const ushort* __restrict__ WF,  // layer base: [4][2048][8] bf16
    const float* __restrict__ rs,   // [4][n]
    ushort* __restrict__ yb,        // [4][n*D]
    int n) {
    const int p = blockIdx.y;
    const float* X = p ? XB : XA;
    const int e0 = 2 * p, e1 = 2 * p + 1;
    const short8* F0 = (const short8*)(WF + (size_t)e0 * 16384);
    const short8* F1 = (const short8*)(WF + (size_t)e1 * 16384);
    const float* rs0 = rs + (size_t)e0 * n;
    const float* rs1 = rs + (size_t)e1 * n;
    ushort* Y0 = yb + (size_t)e0 * n * D;
    ushort* Y1 = yb + (size_t)e1 * n * D;
    const int lane = threadIdx.x & 63;
    const int m = lane & 15, q = lane >> 4;
    const int wave = blockIdx.x * 4 + (threadIdx.x >> 6);
    const int nw = gridDim.x * 4;
    const int nstrips = (n + 15) >> 4;
    for (int sidx = wave; sidx < nstrips; sidx += nw) {
        const int r = sidx * 16 + m;
        const int rc = r < n ? r : n - 1;
        const float* xp = X + (size_t)rc * D + q * 8;
        short8 xf[4];
#pragma unroll
        for (int kf = 0; kf < 4; ++kf) {
            float4 u0 = *(const float4*)(xp + kf * 32);
            float4 u1 = *(const float4*)(xp + kf * 32 + 4);
            short8 v;
            v[0] = (short)f2bf(u0.x); v[1] = (short)f2bf(u0.y);
            v[2] = (short)f2bf(u0.z); v[3] = (short)f2bf(u0.w);
            v[4] = (short)f2bf(u1.x); v[5] = (short)f2bf(u1.y);
            v[6] = (short)f2bf(u1.z); v[7] = (short)f2bf(u1.w);
            xf[kf] = v;
        }
        f32x4 a0[8], a1[8];
#pragma unroll
        for (int ct = 0; ct < 8; ++ct) {
            a0[ct] = (f32x4){0.f, 0.f, 0.f, 0.f};
            a1[ct] = (f32x4){0.f, 0.f, 0.f, 0.f};
        }
#pragma unroll
        for (int ct = 0; ct < 8; ++ct)
#pragma unroll
            for (int kf = 0; kf < 4; ++kf) {
                a0[ct] = __builtin_amdgcn_mfma_f32_16x16x32_bf16(
                    F0[(ct * 4 + kf) * 64 + lane], xf[kf], a0[ct], 0, 0, 0);
                a1[ct] = __builtin_amdgcn_mfma_f32_16x16x32_bf16(
                    F1[(ct * 4 + kf) * 64 + lane], xf[kf], a1[ct], 0, 0, 0);
            }
        if (r < n) {
            float s0v = rs0[r], s1v = rs1[r];
            ushort* y0r = Y0 + (size_t)r * D + q * 4;
            ushort* y1r = Y1 + (size_t)r * D + q * 4;
#pragma unroll
            for (int ct = 0; ct < 8; ++ct) {
                uint2 w;
                w.x = (uint)f2bf(a0[ct][0] * s0v) | ((uint)f2bf(a0[ct][1] * s0v) << 16);
                w.y = (uint)f2bf(a0[ct][2] * s0v) | ((uint)f2bf(a0[ct][3] * s0v) << 16);
                *(uint2*)(y0r + ct * 16) = w;
                uint2 z;
                z.x = (uint)f2bf(a1[ct][0] * s1v) | ((uint)f2bf(a1[ct][1] * s1v) << 16);
                z.y = (uint)f2bf(a1[ct][2] * s1v) | ((uint)f2bf(a1[ct][3] * s1v) << 16);
                *(uint2*)(y1r + ct * 16) = z;
            }
        }
    }
}

// ---------------- fused dual-relation aggregation + bias + relu + LayerNorm ----------------
// blockIdx.y = dst ntype (0:A rels {0,2}, 1:B rels {1,3}); 1 wave/row, 2 cols/lane
__global__ __launch_bounds__(256) void agg_ln2_k(
    const ushort* __restrict__ yb, const int* __restrict__ csr,
    const int* __restrict__ start, const int* __restrict__ cnt,
    const float* __restrict__ rs_in, const float* __restrict__ bias,
    const float* __restrict__ lng, const float* __restrict__ lnb,
    float* __restrict__ outA, float* __restrict__ outB,
    int N, int E, int act, int layer) {
    const int dt = blockIdx.y;
    const int eA = dt, eB = dt + 2;
    const int lane = threadIdx.x & 63;
    const int row = blockIdx.x * 4 + (threadIdx.x >> 6);
    if (row >= N) return;
    const uint* YuA = (const uint*)(yb + (size_t)eA * N * D);
    const uint* YuB = (const uint*)(yb + (size_t)eB * N * D);
    const int* cAp = csr + (size_t)eA * E;
    const int* cBp = csr + (size_t)eB * E;
    int iA = start[(size_t)eA * N + row], enA = iA + cnt[(size_t)eA * N + row];
    int iB = start[(size_t)eB * N + row], enB = iB + cnt[(size_t)eB * N + row];
    float a0 = 0.f, a1 = 0.f, c0 = 0.f, c1 = 0.f;
    while (iA + 4 <= enA && iB + 4 <= enB) {
        int sa0 = cAp[iA], sa1 = cAp[iA + 1], sa2 = cAp[iA + 2], sa3 = cAp[iA + 3];
        int sb0 = cBp[iB], sb1 = cBp[iB + 1], sb2 = cBp[iB + 2], sb3 = cBp[iB + 3];
        uint pa0 = YuA[(size_t)sa0 * 64 + lane], pa1 = YuA[(size_t)sa1 * 64 + lane];
        uint pa2 = YuA[(size_t)sa2 * 64 + lane], pa3 = YuA[(size_t)sa3 * 64 + lane];
        uint pb0 = YuB[(size_t)sb0 * 64 + lane], pb1 = YuB[(size_t)sb1 * 64 + lane];
        uint pb2 = YuB[(size_t)sb2 * 64 + lane], pb3 = YuB[(size_t)sb3 * 64 + lane];
        a0 += bf2f(pa0 & 0xffffu) + bf2f(pa1 & 0xffffu) + bf2f(pa2 & 0xffffu) + bf2f(pa3 & 0xffffu);
        a1 += bf2f(pa0 >> 16) + bf2f(pa1 >> 16) + bf2f(pa2 >> 16) + bf2f(pa3 >> 16);
        c0 += bf2f(pb0 & 0xffffu) + bf2f(pb1 & 0xffffu) + bf2f(pb2 & 0xffffu) + bf2f(pb3 & 0xffffu);
        c1 += bf2f(pb0 >> 16) + bf2f(pb1 >> 16) + bf2f(pb2 >> 16) + bf2f(pb3 >> 16);
        iA += 4; iB += 4;
    }
    for (; iA + 4 <= enA; iA += 4) {
        int s0 = cAp[iA], s1 = cAp[iA + 1], s2 = cAp[iA + 2], s3 = cAp[iA + 3];
        uint p0 = YuA[(size_t)s0 * 64 + lane], p1 = YuA[(size_t)s1 * 64 + lane];
        uint p2 = YuA[(size_t)s2 * 64 + lane], p3 = YuA[(size_t)s3 * 64 + lane];
        a0 += bf2f(p0 & 0xffffu) + bf2f(p1 & 0xffffu) + bf2f(p2 & 0xffffu) + bf2f(p3 & 0xffffu);
        a1 += bf2f(p0 >> 16) + bf2f(p1 >> 16) + bf2f(p2 >> 16) + bf2f(p3 >> 16);
    }
    for (; iB + 4 <= enB; iB += 4) {
        int s0 = cBp[iB], s1 = cBp[iB + 1], s2 = cBp[iB + 2], s3 = cBp[iB + 3];
        uint p0 = YuB[(size_t)s0 * 64 + lane], p1 = YuB[(size_t)s1 * 64 + lane];
        uint p2 = YuB[(size_t)s2 * 64 + lane], p3 = YuB[(size_t)s3 * 64 + lane];
        c0 += bf2f(p0 & 0xffffu) + bf2f(p1 & 0xffffu) + bf2f(p2 & 0xffffu) + bf2f(p3 & 0xffffu);
        c1 += bf2f(p0 >> 16) + bf2f(p1 >> 16) + bf2f(p2 >> 16) + bf2f(p3 >> 16);
    }
    for (; iA < enA; ++iA) {
        uint p = YuA[(size_t)cAp[iA] * 64 + lane];
        a0 += bf2f(p & 0xffffu); a1 += bf2f(p >> 16);
    }
    for (; iB < enB; ++iB) {
        uint p = YuB[(size_t)cBp[iB] * 64 + lane];
        c0 += bf2f(p & 0xffffu); c1 += bf2f(p >> 16);
    }
    float riA = rs_in[(size_t)eA * N + row], riB = rs_in[(size_t)eB * N + row];
    float2 bA = *(const float2*)(bias + eA * D + lane * 2);
    float2 bB = *(const float2*)(bias + eB * D + lane * 2);
    float v0 = fmaf(a0, riA, bA.x), v1 = fmaf(a1, riA, bA.y);
    float w0 = fmaf(c0, riB, bB.x), w1 = fmaf(c1, riB, bB.y);
    if (act) {
        v0 = fmaxf(v0, 0.f); v1 = fmaxf(v1, 0.f);
        w0 = fmaxf(w0, 0.f); w1 = fmaxf(w1, 0.f);
    }
    v0 += w0; v1 += w1;
    float s = v0 + v1, qq = v0 * v0 + v1 * v1;
#pragma unroll
    for (int off = 1; off < 64; off <<= 1) {
        s += __shfl_xor(s, off);
        qq += __shfl_xor(qq, off);
    }
    float mean = s * (1.f / 128.f);
    float var = qq * (1.f / 128.f) - mean * mean;
    float inv = rsqrtf(var + 1e-5f);
    const int gi = (layer * 2 + dt) * D + lane * 2;
    float2 g = *(const float2*)(lng + gi);
    float2 be = *(const float2*)(lnb + gi);
    float2 o;
    o.x = fmaf((v0 - mean) * inv, g.x, be.x);
    o.y = fmaf((v1 - mean) * inv, g.y, be.y);
    float* OUT = dt ? outB : outA;
    *(float2*)(OUT + (size_t)row * D + lane * 2) = o;
}

extern "C" void kernel_launch(void* const* d_in, const int* in_sizes, int n_in,
                              void* d_out, int out_size, void* d_ws, size_t ws_size,
                              hipStream_t stream) {
    const int N = in_sizes[0] / D;
    const int E = in_sizes[8];
    const float* xA = (const float*)d_in[0];
    const float* xB = (const float*)d_in[1];
    const float* W0 = (const float*)d_in[2];
    const float* b0 = (const float*)d_in[3];
    const float* W1 = (const float*)d_in[4];
    const float* b1 = (const float*)d_in[5];
    const float* lng = (const float*)d_in[6];
    const float* lnb = (const float*)d_in[7];
    const int* s_aa = (const int*)d_in[8];
    const int* d_aa = (const int*)d_in[9];
    const int* s_ab = (const int*)d_in[10];
    const int* d_ab = (const int*)d_in[11];
    const int* s_ba = (const int*)d_in[12];
    const int* d_ba = (const int*)d_in[13];
    const int* s_bb = (const int*)d_in[14];
    const int* d_bb = (const int*)d_in[15];

    const size_t nd = (size_t)N * D;
    char* p = (char*)d_ws;
    ushort* y = (ushort*)p;                 // [4][N*D] bf16
    p += 4 * nd * sizeof(ushort);
    ushort* WF = (ushort*)p;                // [2][4][2048][8] bf16 frag-order
    p += 2 * 4 * 2048 * 8 * sizeof(ushort);
    int* cnt_src = (int*)p;                 // zeroed zone: 8N+16 ints
    int* cnt_dst = cnt_src + 4 * (size_t)N;
    int* totals = cnt_dst + 4 * (size_t)N;
    int* startA = totals + 16;
    int* cursorA = startA + 4 * (size_t)N;
    p = (char*)(cursorA + 4 * (size_t)N);
    float* rs_out = (float*)p;
    float* rs_in = rs_out + 4 * (size_t)N;
    p = (char*)(rs_in + 4 * (size_t)N);
    int* csr = (int*)p;                     // [4][E]

    float* hA = (float*)d_out;
    float* hB = hA + nd;

    hipMemsetAsync(cnt_src, 0, (8 * (size_t)N + 16) * sizeof(int), stream);

    const int TB = 256;
    dim3 eg4((E + 1023) / 1024, 4);
    hist4_k<<<eg4, TB, 0, stream>>>(s_aa, d_aa, s_ab, d_ab, s_ba, d_ba, s_bb, d_bb,
                                    cnt_src, cnt_dst, N, E);
    const int n4 = 4 * N;
    rs_k<<<(n4 + TB - 1) / TB, TB, 0, stream>>>(cnt_src, cnt_dst, rs_out, rs_in, n4);
    dim3 sg4((N + TB - 1) / TB, 4);
    start4_k<<<sg4, TB, 0, stream>>>(cnt_dst, startA, cursorA, totals, N);
    fill4_k<<<eg4, TB, 0, stream>>>(s_aa, d_aa, s_ab, d_ab, s_ba, d_ba, s_bb, d_bb,
                                    cursorA, csr, N, E);
    wswz_k<<<64, TB, 0, stream>>>(W0, W1, WF);

    dim3 gg(384, 2);
    dim3 ag((N + 3) / 4, 2);
    const size_t WFL = 4 * 2048 * 8;  // ushorts per layer

    // layer 0
    gemm_pair_k<<<gg, TB, 0, stream>>>(xA, xB, WF, rs_out, y, N);
    agg_ln2_k<<<ag, TB, 0, stream>>>(y, csr, startA, cnt_dst, rs_in, b0,
                                     lng, lnb, hA, hB, N, E, 1, 0);
    // layer 1
    gemm_pair_k<<<gg, TB, 0, stream>>>(hA, hB, WF + WFL, rs_out, y, N);
    agg_ln2_k<<<ag, TB, 0, stream>>>(y, csr, startA, cnt_dst, rs_in, b1,
                                     lng, lnb, hA, hB, N, E, 0, 1);
}